// Round 9
// baseline (916.917 us; speedup 1.0000x reference)
//
#include <hip/hip_runtime.h>
#include <math.h>

// Problem constants (reference: x[8,2048,1024] f32, W[1024,64] f32)
#define BB 8
#define NN 2048
#define DD 1024
#define EE 64
#define CAP 64
#define NTOK (BB * NN)          // 16384
#define OUT_T_FLOATS 67108864   // 8*2048*64*64 per tensor

typedef float f32x4 __attribute__((ext_vector_type(4)));

// Session ledger (measured):
//   dur = ~340us harness poison-drain + work
//   G(v4)=58 [rep-x3 r4] | S=11 [rep-x3 r5] | sparse~8
//   zeroing out (537MB): memset=~134 (4.0TB/s) | our plain stores=~239
//   (2.2TB/s) | rocclr fill on its 2.147GB buffer = 6.3TB/s.
//   r9 (this): INSTRUMENTED A/B. zeroA (plain stores) x2-rep and zeroB
//   (nontemporal) x2-rep each run ~480us -> both enter rocprof top-5 with
//   their own FETCH_SIZE/WRITE_SIZE/hbm_gbps/Occupancy. Decides whether the
//   out-store path is RFO-bound (fix: nt), flag-insensitive (keep memset,
//   r6=551 is ~floor), or nt-fixable (r10 = nt-zero + sparse ~= 500).

// Workspace layout (bytes):
//   recs      float4[NTOK]   @ 0
//   frecs     float4[NTOK]   @ 262144
//   dens      float[256*64]  @ 524288
//   lossp     float[8]       @ 589824

// ---------------------------------------------------------------------------
// Kernel ZA (diagnostic): plain float4 grid-stride stores, whole output
// buffer, x2 internal rep (asm fence keeps rep-2 stores live).
// ---------------------------------------------------------------------------
__global__ __launch_bounds__(256) void zeroA_plain_kernel(float4* __restrict__ out4)
{
    const size_t n = (size_t)(2 * (size_t)OUT_T_FLOATS) / 4;   // 33,554,432
    const size_t stride = (size_t)gridDim.x * 256;
    const float4 z = make_float4(0.f, 0.f, 0.f, 0.f);
#pragma unroll 1
    for (int rep = 0; rep < 2; ++rep) {
        for (size_t i = (size_t)blockIdx.x * 256 + threadIdx.x; i < n; i += stride)
            out4[i] = z;
        asm volatile("" ::: "memory");
    }
}

// ---------------------------------------------------------------------------
// Kernel ZB (diagnostic): same shape, nontemporal stores.
// ---------------------------------------------------------------------------
__global__ __launch_bounds__(256) void zeroB_nt_kernel(f32x4* __restrict__ out4)
{
    const size_t n = (size_t)(2 * (size_t)OUT_T_FLOATS) / 4;
    const size_t stride = (size_t)gridDim.x * 256;
    const f32x4 z = {0.f, 0.f, 0.f, 0.f};
#pragma unroll 1
    for (int rep = 0; rep < 2; ++rep) {
        for (size_t i = (size_t)blockIdx.x * 256 + threadIdx.x; i < n; i += stride)
            __builtin_nontemporal_store(z, &out4[i]);
        asm volatile("" ::: "memory");
    }
}

// ---------------------------------------------------------------------------
// Kernel G (v4, 609-baseline verbatim): measured 58us.
// ---------------------------------------------------------------------------
__global__ __launch_bounds__(1024, 4) void gating_kernel(
    const float* __restrict__ x, const float* __restrict__ W,
    float4* __restrict__ recs, float* __restrict__ dens)
{
    __shared__ float red[4][64][65];    // [kslice][expert][token+pad] 65 KB
    __shared__ float dred[4][64];

    const int tid  = threadIdx.x;
    const int lane = tid & 63;                                   // token-in-block
    const int wave = __builtin_amdgcn_readfirstlane(tid >> 6);
    const int ks   = wave & 3;                                   // k-slice (256 k)
    const int eq   = wave >> 2;                                  // expert quarter
    const int tok  = blockIdx.x * 64 + lane;

    float acc[16];
#pragma unroll
    for (int j = 0; j < 16; ++j) acc[j] = 0.f;

    const float4* xq = (const float4*)(x + (size_t)tok * DD + ks * 256);
    const float*  wq = W + (size_t)(ks * 256) * EE + eq * 16;    // wave-uniform

#pragma unroll 2
    for (int c = 0; c < 64; ++c) {           // 64 float4 of x = 256 k
        const float4 xv = xq[c];
        const float xs[4] = {xv.x, xv.y, xv.z, xv.w};
#pragma unroll
        for (int kk = 0; kk < 4; ++kk) {
            const float4* wr = (const float4*)(wq + (size_t)(c * 4 + kk) * EE);
            const float4 w0 = wr[0], w1 = wr[1], w2 = wr[2], w3 = wr[3];
            acc[ 0] = fmaf(xs[kk], w0.x, acc[ 0]);
            acc[ 1] = fmaf(xs[kk], w0.y, acc[ 1]);
            acc[ 2] = fmaf(xs[kk], w0.z, acc[ 2]);
            acc[ 3] = fmaf(xs[kk], w0.w, acc[ 3]);
            acc[ 4] = fmaf(xs[kk], w1.x, acc[ 4]);
            acc[ 5] = fmaf(xs[kk], w1.y, acc[ 5]);
            acc[ 6] = fmaf(xs[kk], w1.z, acc[ 6]);
            acc[ 7] = fmaf(xs[kk], w1.w, acc[ 7]);
            acc[ 8] = fmaf(xs[kk], w2.x, acc[ 8]);
            acc[ 9] = fmaf(xs[kk], w2.y, acc[ 9]);
            acc[10] = fmaf(xs[kk], w2.z, acc[10]);
            acc[11] = fmaf(xs[kk], w2.w, acc[11]);
            acc[12] = fmaf(xs[kk], w3.x, acc[12]);
            acc[13] = fmaf(xs[kk], w3.y, acc[13]);
            acc[14] = fmaf(xs[kk], w3.z, acc[14]);
            acc[15] = fmaf(xs[kk], w3.w, acc[15]);
        }
    }

    // ---- one-shot cross-slice reduce via LDS
#pragma unroll
    for (int j = 0; j < 16; ++j)
        red[ks][eq * 16 + j][lane] = acc[j];     // lane stride 1: conflict-free
    __syncthreads();

    // ---- epilogue: waves 0-3, wave w handles tokens [16w,16w+16); lane = expert
    if (wave < 4) {
        const int t0 = wave * 16;
        float densacc = 0.f;
#pragma unroll 1
        for (int ti = 0; ti < 16; ++ti) {
            const int t = t0 + ti;
            const float lv = ((red[0][lane][t] + red[1][lane][t])
                            + red[2][lane][t]) + red[3][lane][t];  // stride 65: free

            // argmax: value desc, index asc on ties (matches jnp.argmax)
            float v = lv; int bi = lane;
#pragma unroll
            for (int off = 32; off; off >>= 1) {
                float ov = __shfl_xor(v, off);
                int   oi = __shfl_xor(bi, off);
                if (ov > v || (ov == v && oi < bi)) { v = ov; bi = oi; }
            }
            const float m1 = v; const int i1 = bi;
            float v2 = (lane == i1) ? -INFINITY : lv; int b2 = lane;
#pragma unroll
            for (int off = 32; off; off >>= 1) {
                float ov = __shfl_xor(v2, off);
                int   oi = __shfl_xor(b2, off);
                if (ov > v2 || (ov == v2 && oi < b2)) { v2 = ov; b2 = oi; }
            }
            const float m2 = v2; const int i2 = b2;

            float ex = expf(lv - m1);
            float Z = ex;
#pragma unroll
            for (int off = 32; off; off >>= 1) Z += __shfl_xor(Z, off);
            float g1 = 1.0f / Z;               // p[i1]
            float g2 = expf(m2 - m1) * g1;     // p[i2]
            float den = g1 + g2 + 1e-9f;
            float g1n = g1 / den;
            float g2n = g2 / den;
            int flag = (g2n > 0.2f) ? 1 : 0;   // threshold on NORMALIZED gate_2

            densacc += ex * g1;                // p_t[lane] for density proxy

            if (lane == 0)
                recs[blockIdx.x * 64 + t] =
                    make_float4(g1n, g2n, __int_as_float(i1),
                                __int_as_float(i2 | (flag << 8)));
        }
        dred[wave][lane] = densacc;
    }
    __syncthreads();
    if (tid < 64) {
        float s = dred[0][tid] + dred[1][tid] + dred[2][tid] + dred[3][tid];
        dens[blockIdx.x * 64 + tid] = s;       // per-block partial, no atomics
    }
}

// ---------------------------------------------------------------------------
// Kernel S (609-baseline verbatim): measured 11us.
// ---------------------------------------------------------------------------
__global__ __launch_bounds__(1024) void scan_kernel(
    const float4* __restrict__ recs, const float* __restrict__ dens,
    float4* __restrict__ frecs, float* __restrict__ lossp)
{
    const int b = blockIdx.x;
    __shared__ int hist1[32][64], pre1[32][64];
    __shared__ int hist2[32][64], pre2[32][64];
    __shared__ int base2[64];
    __shared__ float dsum[64];

    const int tid = threadIdx.x;
    const int lane = tid & 63;
    const int wave = tid >> 6;

    float4 r[2];
    int e1[2], e2[2], fl[2], rank1[2], rank2[2];
    const unsigned long long below = (1ull << lane) - 1ull;

#pragma unroll
    for (int u = 0; u < 2; ++u) {
        const int g = 2 * wave + u;
        const int tok = g * 64 + lane;
        float4 rr = recs[b * NN + tok];
        r[u] = rr;
        e1[u] = __float_as_int(rr.z);
        int i2f = __float_as_int(rr.w);
        e2[u] = i2f & 63;
        fl[u] = i2f >> 8;

        unsigned long long m = ~0ull, mv = ~0ull;
#pragma unroll
        for (int bit = 0; bit < 6; ++bit) {
            unsigned long long vt = __ballot((e1[u] >> bit) & 1);
            m  &= ((e1[u] >> bit) & 1) ? vt : ~vt;
            mv &= ((lane  >> bit) & 1) ? vt : ~vt;
        }
        rank1[u] = __popcll(m & below);
        hist1[g][lane] = __popcll(mv);

        unsigned long long fv = __ballot(fl[u]);
        m = fv; mv = fv;
#pragma unroll
        for (int bit = 0; bit < 6; ++bit) {
            unsigned long long vt = __ballot((e2[u] >> bit) & 1);
            m  &= ((e2[u] >> bit) & 1) ? vt : ~vt;
            mv &= ((lane  >> bit) & 1) ? vt : ~vt;
        }
        rank2[u] = __popcll(m & below);
        hist2[g][lane] = __popcll(mv);
    }

    if (wave == 0) {  // density sums: 32 gating blocks per batch
        float s = 0.f;
        for (int k = 0; k < 32; ++k) s += dens[(b * 32 + k) * 64 + lane];
        dsum[lane] = s;
    }
    __syncthreads();

    if (wave == 0) {  // cross-group exclusive prefix, lane = expert
        int run = 0;
#pragma unroll
        for (int g = 0; g < 32; ++g) { pre1[g][lane] = run; run += hist1[g][lane]; }
        base2[lane] = run < CAP ? run : CAP;     // mask_1_count = min(count, cap)
        int run2 = 0;
#pragma unroll
        for (int g = 0; g < 32; ++g) { pre2[g][lane] = run2; run2 += hist2[g][lane]; }
        float v = dsum[lane] * (float)run;       // UNCAPPED count for loss
#pragma unroll
        for (int off = 32; off; off >>= 1) v += __shfl_xor(v, off);
        if (lane == 0) lossp[b] = v;
    }
    __syncthreads();

#pragma unroll
    for (int u = 0; u < 2; ++u) {
        const int g = 2 * wave + u;
        const int tok = g * 64 + lane;
        int p1 = rank1[u] + pre1[g][e1[u]];
        int k1 = p1 < CAP;
        int p2 = rank2[u] + pre2[g][e2[u]] + base2[e2[u]];
        int k2 = fl[u] && (p2 < CAP);
        float4 fr;
        fr.x = k1 ? r[u].x : 0.f;
        fr.y = k2 ? r[u].y : 0.f;
        fr.z = __int_as_float(k1 ? (e1[u] * CAP + p1) : -1);
        fr.w = __int_as_float(k2 ? (e2[u] * CAP + p2) : -1);
        frecs[b * NN + tok] = fr;
    }
}

// ---------------------------------------------------------------------------
// Kernel F (sparse, r6 verbatim): out already zeroed. Scatter the <=2
// nonzero (expert,pos) slots per token per tensor + loss scalar.
// ---------------------------------------------------------------------------
__global__ __launch_bounds__(256) void sparse_fill_kernel(
    const float4* __restrict__ frecs, const float* __restrict__ lossp,
    float* __restrict__ out)
{
    const int token = blockIdx.x * 256 + threadIdx.x;   // 0 .. 16383
    const float4 r = frecs[token];
    float* __restrict__ dsp = out;
    float* __restrict__ cmb = out + (size_t)OUT_T_FLOATS;
    const size_t base = (size_t)token * (EE * CAP);

    const int p1 = __float_as_int(r.z);
    if (p1 >= 0) {
        dsp[base + p1] = 1.0f;
        cmb[base + p1] = r.x;
    }
    const int p2 = __float_as_int(r.w);
    if (p2 >= 0) {
        dsp[base + p2] = 1.0f;
        cmb[base + p2] = r.y;
    }

    if (token == 0) {
        float s = 0.f;
        for (int k = 0; k < 8; ++k) s += lossp[k];
        // loss = sum_b lossp[b] * e^2 / (b*e*n^2) = s / 524288
        out[2 * (size_t)OUT_T_FLOATS] = s * (1.0f / 524288.0f);
    }
}

extern "C" void kernel_launch(void* const* d_in, const int* in_sizes, int n_in,
                              void* d_out, int out_size, void* d_ws, size_t ws_size,
                              hipStream_t stream)
{
    const float* x = (const float*)d_in[0];
    const float* W = (const float*)d_in[1];
    float* out = (float*)d_out;
    char* ws = (char*)d_ws;

    float4* recs  = (float4*)(ws);
    float4* frecs = (float4*)(ws + 262144);
    float*  dens  = (float*)(ws + 524288);
    float*  lossp = (float*)(ws + 589824);

    // DIAGNOSTIC round: both zero variants run x2 internally (idempotent;
    // buffer ends correctly zeroed). Their counters land in the top-5.
    zeroA_plain_kernel<<<2048, 256, 0, stream>>>((float4*)out);
    zeroB_nt_kernel<<<2048, 256, 0, stream>>>((f32x4*)out);

    gating_kernel<<<256, 1024, 0, stream>>>(x, W, recs, dens);
    scan_kernel<<<8, 1024, 0, stream>>>(recs, dens, frecs, lossp);
    sparse_fill_kernel<<<NTOK / 256, 256, 0, stream>>>(frecs, lossp, out);
}

// Round 10
// 635.603 us; speedup vs baseline: 1.4426x; 1.4426x over previous
//
#include <hip/hip_runtime.h>
#include <math.h>

// Problem constants (reference: x[8,2048,1024] f32, W[1024,64] f32)
#define BB 8
#define NN 2048
#define DD 1024
#define EE 64
#define CAP 64
#define NTOK (BB * NN)          // 16384
#define OUT_T_FLOATS 67108864   // 8*2048*64*64 per tensor

// Session ledger (measured):
//   dur = ~340us harness poison-drain + work
//   G(v4,16w)=58 [rep-x3 r4] | S=11 [rep-x3 r5] | sparse~8
//   out-zero floor = (537MB + ~288MB poison writeback) @ 6.2TB/s ~= 134us;
//   memset achieves it (r6=551). First-toucher of out pays the writeback:
//   r8 plain zero 1st pass=239; repeat passes=87 (r9: ZA=326=239+87,
//   ZB=174=87+87, sum 500 ✓). r7 wave-level store fusion FAILED (per-wave
//   vmcnt entangles x-loads with out-stores).
//   r10 (this): BLOCK-level specialization — one kernel, 512 blocks x 512thr:
//   blocks 0-255 gating (8 waves = 2 k-halves x 4 eq), blocks 256-511 zero
//   2MiB slices. 1+1 blocks/CU = 16 waves @ <=128 VGPR co-resident; zero
//   waves' stores have their own vmcnt -> true overlap. Fused floor ~= 140.

// Workspace layout (bytes):
//   recs      float4[NTOK]   @ 0
//   frecs     float4[NTOK]   @ 262144
//   dens      float[256*64]  @ 524288
//   lossp     float[8]       @ 589824

// ---------------------------------------------------------------------------
// Kernel GZ: fused gating + output zeroing via block specialization.
// ---------------------------------------------------------------------------
__global__ __launch_bounds__(512, 4) void gz_kernel(
    const float* __restrict__ x, const float* __restrict__ W,
    float4* __restrict__ recs, float* __restrict__ dens,
    float4* __restrict__ outz)
{
    // ---- zero blocks: 256..511, each zeroes a contiguous 2 MiB slice -----
    if (blockIdx.x >= 256) {
        const int zb = blockIdx.x - 256;
        float4* dst = outz + (size_t)zb * 131072;   // 131072 f4 = 2 MiB
        const float4 z = make_float4(0.f, 0.f, 0.f, 0.f);
#pragma unroll 4
        for (int j = threadIdx.x; j < 131072; j += 512)
            dst[j] = z;
        return;
    }

    // ---- gating blocks: 0..255 (v4 body, 8-wave form: kh x eq) -----------
    __shared__ float red[2][64][65];    // [k-half][expert][token+pad] 33 KB
    __shared__ float dred[4][64];

    const int tid  = threadIdx.x;
    const int lane = tid & 63;                                   // token-in-block
    const int wave = __builtin_amdgcn_readfirstlane(tid >> 6);   // 0..7
    const int kh   = wave & 1;                                   // k-half (512 k)
    const int eq   = wave >> 1;                                  // expert quarter
    const int tok  = blockIdx.x * 64 + lane;

    float acc[16];
#pragma unroll
    for (int j = 0; j < 16; ++j) acc[j] = 0.f;

    const float4* xq = (const float4*)(x + (size_t)tok * DD + kh * 512);
    const float*  wq = W + (size_t)(kh * 512) * EE + eq * 16;    // wave-uniform

#pragma unroll 2
    for (int c = 0; c < 128; ++c) {          // 128 float4 of x = 512 k
        const float4 xv = xq[c];
        const float xs[4] = {xv.x, xv.y, xv.z, xv.w};
#pragma unroll
        for (int kk = 0; kk < 4; ++kk) {
            const float4* wr = (const float4*)(wq + (size_t)(c * 4 + kk) * EE);
            const float4 w0 = wr[0], w1 = wr[1], w2 = wr[2], w3 = wr[3];
            acc[ 0] = fmaf(xs[kk], w0.x, acc[ 0]);
            acc[ 1] = fmaf(xs[kk], w0.y, acc[ 1]);
            acc[ 2] = fmaf(xs[kk], w0.z, acc[ 2]);
            acc[ 3] = fmaf(xs[kk], w0.w, acc[ 3]);
            acc[ 4] = fmaf(xs[kk], w1.x, acc[ 4]);
            acc[ 5] = fmaf(xs[kk], w1.y, acc[ 5]);
            acc[ 6] = fmaf(xs[kk], w1.z, acc[ 6]);
            acc[ 7] = fmaf(xs[kk], w1.w, acc[ 7]);
            acc[ 8] = fmaf(xs[kk], w2.x, acc[ 8]);
            acc[ 9] = fmaf(xs[kk], w2.y, acc[ 9]);
            acc[10] = fmaf(xs[kk], w2.z, acc[10]);
            acc[11] = fmaf(xs[kk], w2.w, acc[11]);
            acc[12] = fmaf(xs[kk], w3.x, acc[12]);
            acc[13] = fmaf(xs[kk], w3.y, acc[13]);
            acc[14] = fmaf(xs[kk], w3.z, acc[14]);
            acc[15] = fmaf(xs[kk], w3.w, acc[15]);
        }
    }

    // ---- cross-half reduce via LDS
#pragma unroll
    for (int j = 0; j < 16; ++j)
        red[kh][eq * 16 + j][lane] = acc[j];     // lane stride 1: conflict-free
    __syncthreads();

    // ---- epilogue: waves 0-3, wave w handles tokens [16w,16w+16); lane = expert
    if (wave < 4) {
        const int t0 = wave * 16;
        float densacc = 0.f;
#pragma unroll 1
        for (int ti = 0; ti < 16; ++ti) {
            const int t = t0 + ti;
            const float lv = red[0][lane][t] + red[1][lane][t];  // stride 65: free

            // argmax: value desc, index asc on ties (matches jnp.argmax)
            float v = lv; int bi = lane;
#pragma unroll
            for (int off = 32; off; off >>= 1) {
                float ov = __shfl_xor(v, off);
                int   oi = __shfl_xor(bi, off);
                if (ov > v || (ov == v && oi < bi)) { v = ov; bi = oi; }
            }
            const float m1 = v; const int i1 = bi;
            float v2 = (lane == i1) ? -INFINITY : lv; int b2 = lane;
#pragma unroll
            for (int off = 32; off; off >>= 1) {
                float ov = __shfl_xor(v2, off);
                int   oi = __shfl_xor(b2, off);
                if (ov > v2 || (ov == v2 && oi < b2)) { v2 = ov; b2 = oi; }
            }
            const float m2 = v2; const int i2 = b2;

            float ex = expf(lv - m1);
            float Z = ex;
#pragma unroll
            for (int off = 32; off; off >>= 1) Z += __shfl_xor(Z, off);
            float g1 = 1.0f / Z;               // p[i1]
            float g2 = expf(m2 - m1) * g1;     // p[i2]
            float den = g1 + g2 + 1e-9f;
            float g1n = g1 / den;
            float g2n = g2 / den;
            int flag = (g2n > 0.2f) ? 1 : 0;   // threshold on NORMALIZED gate_2

            densacc += ex * g1;                // p_t[lane] for density proxy

            if (lane == 0)
                recs[blockIdx.x * 64 + t] =
                    make_float4(g1n, g2n, __int_as_float(i1),
                                __int_as_float(i2 | (flag << 8)));
        }
        dred[wave][lane] = densacc;
    }
    __syncthreads();
    if (tid < 64) {
        float s = dred[0][tid] + dred[1][tid] + dred[2][tid] + dred[3][tid];
        dens[blockIdx.x * 64 + tid] = s;       // per-block partial, no atomics
    }
}

// ---------------------------------------------------------------------------
// Kernel S (609-baseline verbatim): measured 11us.
// ---------------------------------------------------------------------------
__global__ __launch_bounds__(1024) void scan_kernel(
    const float4* __restrict__ recs, const float* __restrict__ dens,
    float4* __restrict__ frecs, float* __restrict__ lossp)
{
    const int b = blockIdx.x;
    __shared__ int hist1[32][64], pre1[32][64];
    __shared__ int hist2[32][64], pre2[32][64];
    __shared__ int base2[64];
    __shared__ float dsum[64];

    const int tid = threadIdx.x;
    const int lane = tid & 63;
    const int wave = tid >> 6;

    float4 r[2];
    int e1[2], e2[2], fl[2], rank1[2], rank2[2];
    const unsigned long long below = (1ull << lane) - 1ull;

#pragma unroll
    for (int u = 0; u < 2; ++u) {
        const int g = 2 * wave + u;
        const int tok = g * 64 + lane;
        float4 rr = recs[b * NN + tok];
        r[u] = rr;
        e1[u] = __float_as_int(rr.z);
        int i2f = __float_as_int(rr.w);
        e2[u] = i2f & 63;
        fl[u] = i2f >> 8;

        unsigned long long m = ~0ull, mv = ~0ull;
#pragma unroll
        for (int bit = 0; bit < 6; ++bit) {
            unsigned long long vt = __ballot((e1[u] >> bit) & 1);
            m  &= ((e1[u] >> bit) & 1) ? vt : ~vt;
            mv &= ((lane  >> bit) & 1) ? vt : ~vt;
        }
        rank1[u] = __popcll(m & below);
        hist1[g][lane] = __popcll(mv);

        unsigned long long fv = __ballot(fl[u]);
        m = fv; mv = fv;
#pragma unroll
        for (int bit = 0; bit < 6; ++bit) {
            unsigned long long vt = __ballot((e2[u] >> bit) & 1);
            m  &= ((e2[u] >> bit) & 1) ? vt : ~vt;
            mv &= ((lane  >> bit) & 1) ? vt : ~vt;
        }
        rank2[u] = __popcll(m & below);
        hist2[g][lane] = __popcll(mv);
    }

    if (wave == 0) {  // density sums: 32 gating blocks per batch
        float s = 0.f;
        for (int k = 0; k < 32; ++k) s += dens[(b * 32 + k) * 64 + lane];
        dsum[lane] = s;
    }
    __syncthreads();

    if (wave == 0) {  // cross-group exclusive prefix, lane = expert
        int run = 0;
#pragma unroll
        for (int g = 0; g < 32; ++g) { pre1[g][lane] = run; run += hist1[g][lane]; }
        base2[lane] = run < CAP ? run : CAP;     // mask_1_count = min(count, cap)
        int run2 = 0;
#pragma unroll
        for (int g = 0; g < 32; ++g) { pre2[g][lane] = run2; run2 += hist2[g][lane]; }
        float v = dsum[lane] * (float)run;       // UNCAPPED count for loss
#pragma unroll
        for (int off = 32; off; off >>= 1) v += __shfl_xor(v, off);
        if (lane == 0) lossp[b] = v;
    }
    __syncthreads();

#pragma unroll
    for (int u = 0; u < 2; ++u) {
        const int g = 2 * wave + u;
        const int tok = g * 64 + lane;
        int p1 = rank1[u] + pre1[g][e1[u]];
        int k1 = p1 < CAP;
        int p2 = rank2[u] + pre2[g][e2[u]] + base2[e2[u]];
        int k2 = fl[u] && (p2 < CAP);
        float4 fr;
        fr.x = k1 ? r[u].x : 0.f;
        fr.y = k2 ? r[u].y : 0.f;
        fr.z = __int_as_float(k1 ? (e1[u] * CAP + p1) : -1);
        fr.w = __int_as_float(k2 ? (e2[u] * CAP + p2) : -1);
        frecs[b * NN + tok] = fr;
    }
}

// ---------------------------------------------------------------------------
// Kernel F (sparse, r6 verbatim): out already zeroed by gz. Scatter the <=2
// nonzero (expert,pos) slots per token per tensor + loss scalar.
// ---------------------------------------------------------------------------
__global__ __launch_bounds__(256) void sparse_fill_kernel(
    const float4* __restrict__ frecs, const float* __restrict__ lossp,
    float* __restrict__ out)
{
    const int token = blockIdx.x * 256 + threadIdx.x;   // 0 .. 16383
    const float4 r = frecs[token];
    float* __restrict__ dsp = out;
    float* __restrict__ cmb = out + (size_t)OUT_T_FLOATS;
    const size_t base = (size_t)token * (EE * CAP);

    const int p1 = __float_as_int(r.z);
    if (p1 >= 0) {
        dsp[base + p1] = 1.0f;
        cmb[base + p1] = r.x;
    }
    const int p2 = __float_as_int(r.w);
    if (p2 >= 0) {
        dsp[base + p2] = 1.0f;
        cmb[base + p2] = r.y;
    }

    if (token == 0) {
        float s = 0.f;
        for (int k = 0; k < 8; ++k) s += lossp[k];
        // loss = sum_b lossp[b] * e^2 / (b*e*n^2) = s / 524288
        out[2 * (size_t)OUT_T_FLOATS] = s * (1.0f / 524288.0f);
    }
}

extern "C" void kernel_launch(void* const* d_in, const int* in_sizes, int n_in,
                              void* d_out, int out_size, void* d_ws, size_t ws_size,
                              hipStream_t stream)
{
    const float* x = (const float*)d_in[0];
    const float* W = (const float*)d_in[1];
    float* out = (float*)d_out;
    char* ws = (char*)d_ws;

    float4* recs  = (float4*)(ws);
    float4* frecs = (float4*)(ws + 262144);
    float*  dens  = (float*)(ws + 524288);
    float*  lossp = (float*)(ws + 589824);

    gz_kernel<<<512, 512, 0, stream>>>(x, W, recs, dens, (float4*)out);
    scan_kernel<<<8, 1024, 0, stream>>>(recs, dens, frecs, lossp);
    sparse_fill_kernel<<<NTOK / 256, 256, 0, stream>>>(frecs, lossp, out);
}

// Round 11
// 555.272 us; speedup vs baseline: 1.6513x; 1.1447x over previous
//
#include <hip/hip_runtime.h>
#include <math.h>

// Problem constants (reference: x[8,2048,1024] f32, W[1024,64] f32)
#define BB 8
#define NN 2048
#define DD 1024
#define EE 64
#define CAP 64
#define NTOK (BB * NN)          // 16384
#define OUT_T_FLOATS 67108864   // 8*2048*64*64 per tensor

// Session ledger (measured):
//   dur = ~340us harness poison-drain + work
//   G(v4,16w)=58 [rep-x3 r4] | S=11 [rep-x3 r5] | sparse~8
//   zero phase floor = 134us (hipMemsetAsync; includes ~288MB poison
//   writeback at 6.15TB/s effective). Our kernels first-touch out at only
//   3.45TB/s (r8/r9); repeat passes full 6.2 (r9).
//   OVERLAP DEAD END (0/3): r7 wave-fusion (vmcnt entangles loads+stores),
//   r10 block-specialization (zero stores starve gating's 64-line
//   uncoalesced loads; gating 58 -> ~277). Dropped.
//   r11 (this): banked-r6 skeleton + two low-risk deltas:
//     (a) G c-loop unroll 2->4 (x-load latency ~450cyc LLC-warm, only 2
//         loads in flight; 4 doubles coverage; +8 VGPR < 128 cap)
//     (b) scan directly scatters the <=4 out-dwords/token + atomicAdd loss
//         (out L2-warm after memset) -> sparse kernel deleted.

// Workspace layout (bytes):
//   recs      float4[NTOK]   @ 0
//   dens      float[256*64]  @ 524288
//   (frecs/lossp no longer used; scan writes out directly)

// ---------------------------------------------------------------------------
// Kernel G (v4 + unroll 4): 256 blocks x 1024 threads; block owns 64 tokens
// (lane = token). 16 waves = 4 k-slices x 4 expert-quarters, acc[16]/thread.
// ---------------------------------------------------------------------------
__global__ __launch_bounds__(1024, 4) void gating_kernel(
    const float* __restrict__ x, const float* __restrict__ W,
    float4* __restrict__ recs, float* __restrict__ dens)
{
    __shared__ float red[4][64][65];    // [kslice][expert][token+pad] 65 KB
    __shared__ float dred[4][64];

    const int tid  = threadIdx.x;
    const int lane = tid & 63;                                   // token-in-block
    const int wave = __builtin_amdgcn_readfirstlane(tid >> 6);
    const int ks   = wave & 3;                                   // k-slice (256 k)
    const int eq   = wave >> 2;                                  // expert quarter
    const int tok  = blockIdx.x * 64 + lane;

    float acc[16];
#pragma unroll
    for (int j = 0; j < 16; ++j) acc[j] = 0.f;

    const float4* xq = (const float4*)(x + (size_t)tok * DD + ks * 256);
    const float*  wq = W + (size_t)(ks * 256) * EE + eq * 16;    // wave-uniform

#pragma unroll 4
    for (int c = 0; c < 64; ++c) {           // 64 float4 of x = 256 k
        const float4 xv = xq[c];
        const float xs[4] = {xv.x, xv.y, xv.z, xv.w};
#pragma unroll
        for (int kk = 0; kk < 4; ++kk) {
            const float4* wr = (const float4*)(wq + (size_t)(c * 4 + kk) * EE);
            const float4 w0 = wr[0], w1 = wr[1], w2 = wr[2], w3 = wr[3];
            acc[ 0] = fmaf(xs[kk], w0.x, acc[ 0]);
            acc[ 1] = fmaf(xs[kk], w0.y, acc[ 1]);
            acc[ 2] = fmaf(xs[kk], w0.z, acc[ 2]);
            acc[ 3] = fmaf(xs[kk], w0.w, acc[ 3]);
            acc[ 4] = fmaf(xs[kk], w1.x, acc[ 4]);
            acc[ 5] = fmaf(xs[kk], w1.y, acc[ 5]);
            acc[ 6] = fmaf(xs[kk], w1.z, acc[ 6]);
            acc[ 7] = fmaf(xs[kk], w1.w, acc[ 7]);
            acc[ 8] = fmaf(xs[kk], w2.x, acc[ 8]);
            acc[ 9] = fmaf(xs[kk], w2.y, acc[ 9]);
            acc[10] = fmaf(xs[kk], w2.z, acc[10]);
            acc[11] = fmaf(xs[kk], w2.w, acc[11]);
            acc[12] = fmaf(xs[kk], w3.x, acc[12]);
            acc[13] = fmaf(xs[kk], w3.y, acc[13]);
            acc[14] = fmaf(xs[kk], w3.z, acc[14]);
            acc[15] = fmaf(xs[kk], w3.w, acc[15]);
        }
    }

    // ---- one-shot cross-slice reduce via LDS
#pragma unroll
    for (int j = 0; j < 16; ++j)
        red[ks][eq * 16 + j][lane] = acc[j];     // lane stride 1: conflict-free
    __syncthreads();

    // ---- epilogue: waves 0-3, wave w handles tokens [16w,16w+16); lane = expert
    if (wave < 4) {
        const int t0 = wave * 16;
        float densacc = 0.f;
#pragma unroll 1
        for (int ti = 0; ti < 16; ++ti) {
            const int t = t0 + ti;
            const float lv = ((red[0][lane][t] + red[1][lane][t])
                            + red[2][lane][t]) + red[3][lane][t];  // stride 65: free

            // argmax: value desc, index asc on ties (matches jnp.argmax)
            float v = lv; int bi = lane;
#pragma unroll
            for (int off = 32; off; off >>= 1) {
                float ov = __shfl_xor(v, off);
                int   oi = __shfl_xor(bi, off);
                if (ov > v || (ov == v && oi < bi)) { v = ov; bi = oi; }
            }
            const float m1 = v; const int i1 = bi;
            float v2 = (lane == i1) ? -INFINITY : lv; int b2 = lane;
#pragma unroll
            for (int off = 32; off; off >>= 1) {
                float ov = __shfl_xor(v2, off);
                int   oi = __shfl_xor(b2, off);
                if (ov > v2 || (ov == v2 && oi < b2)) { v2 = ov; b2 = oi; }
            }
            const float m2 = v2; const int i2 = b2;

            float ex = expf(lv - m1);
            float Z = ex;
#pragma unroll
            for (int off = 32; off; off >>= 1) Z += __shfl_xor(Z, off);
            float g1 = 1.0f / Z;               // p[i1]
            float g2 = expf(m2 - m1) * g1;     // p[i2]
            float den = g1 + g2 + 1e-9f;
            float g1n = g1 / den;
            float g2n = g2 / den;
            int flag = (g2n > 0.2f) ? 1 : 0;   // threshold on NORMALIZED gate_2

            densacc += ex * g1;                // p_t[lane] for density proxy

            if (lane == 0)
                recs[blockIdx.x * 64 + t] =
                    make_float4(g1n, g2n, __int_as_float(i1),
                                __int_as_float(i2 | (flag << 8)));
        }
        dred[wave][lane] = densacc;
    }
    __syncthreads();
    if (tid < 64) {
        float s = dred[0][tid] + dred[1][tid] + dred[2][tid] + dred[3][tid];
        dens[blockIdx.x * 64 + tid] = s;       // per-block partial, no atomics
    }
}

// ---------------------------------------------------------------------------
// Kernel S (fused scatter): ballot-rank scan (verbatim logic) + DIRECT
// scatter of the <=2 nonzero (expert,pos) dwords per token per tensor into
// out (L2-warm after the in-stream memset), + atomicAdd of the loss partial
// (out[loss] zeroed by the same memset each iteration; device-scope default).
// 1 block/batch, 1024 threads.
// ---------------------------------------------------------------------------
__global__ __launch_bounds__(1024) void scan_scatter_kernel(
    const float4* __restrict__ recs, const float* __restrict__ dens,
    float* __restrict__ out)
{
    const int b = blockIdx.x;
    __shared__ int hist1[32][64], pre1[32][64];
    __shared__ int hist2[32][64], pre2[32][64];
    __shared__ int base2[64];
    __shared__ float dsum[64];

    const int tid = threadIdx.x;
    const int lane = tid & 63;
    const int wave = tid >> 6;

    float4 r[2];
    int e1[2], e2[2], fl[2], rank1[2], rank2[2];
    const unsigned long long below = (1ull << lane) - 1ull;

#pragma unroll
    for (int u = 0; u < 2; ++u) {
        const int g = 2 * wave + u;
        const int tok = g * 64 + lane;
        float4 rr = recs[b * NN + tok];
        r[u] = rr;
        e1[u] = __float_as_int(rr.z);
        int i2f = __float_as_int(rr.w);
        e2[u] = i2f & 63;
        fl[u] = i2f >> 8;

        unsigned long long m = ~0ull, mv = ~0ull;
#pragma unroll
        for (int bit = 0; bit < 6; ++bit) {
            unsigned long long vt = __ballot((e1[u] >> bit) & 1);
            m  &= ((e1[u] >> bit) & 1) ? vt : ~vt;
            mv &= ((lane  >> bit) & 1) ? vt : ~vt;
        }
        rank1[u] = __popcll(m & below);
        hist1[g][lane] = __popcll(mv);

        unsigned long long fv = __ballot(fl[u]);
        m = fv; mv = fv;
#pragma unroll
        for (int bit = 0; bit < 6; ++bit) {
            unsigned long long vt = __ballot((e2[u] >> bit) & 1);
            m  &= ((e2[u] >> bit) & 1) ? vt : ~vt;
            mv &= ((lane  >> bit) & 1) ? vt : ~vt;
        }
        rank2[u] = __popcll(m & below);
        hist2[g][lane] = __popcll(mv);
    }

    if (wave == 0) {  // density sums: 32 gating blocks per batch
        float s = 0.f;
        for (int k = 0; k < 32; ++k) s += dens[(b * 32 + k) * 64 + lane];
        dsum[lane] = s;
    }
    __syncthreads();

    if (wave == 0) {  // cross-group exclusive prefix, lane = expert
        int run = 0;
#pragma unroll
        for (int g = 0; g < 32; ++g) { pre1[g][lane] = run; run += hist1[g][lane]; }
        base2[lane] = run < CAP ? run : CAP;     // mask_1_count = min(count, cap)
        int run2 = 0;
#pragma unroll
        for (int g = 0; g < 32; ++g) { pre2[g][lane] = run2; run2 += hist2[g][lane]; }
        float v = dsum[lane] * (float)run;       // UNCAPPED count for loss
#pragma unroll
        for (int off = 32; off; off >>= 1) v += __shfl_xor(v, off);
        if (lane == 0)
            // loss = sum_b v_b * e^2 / (b*e*n^2) = sum_b v_b / 524288
            atomicAdd(out + 2 * (size_t)OUT_T_FLOATS, v * (1.0f / 524288.0f));
    }
    __syncthreads();

    float* __restrict__ dsp = out;
    float* __restrict__ cmb = out + (size_t)OUT_T_FLOATS;

#pragma unroll
    for (int u = 0; u < 2; ++u) {
        const int g = 2 * wave + u;
        const int tok = g * 64 + lane;
        const size_t tb = (size_t)(b * NN + tok) * (EE * CAP);
        int p1 = rank1[u] + pre1[g][e1[u]];
        if (p1 < CAP) {
            const size_t o = tb + e1[u] * CAP + p1;
            dsp[o] = 1.0f;
            cmb[o] = r[u].x;
        }
        int p2 = rank2[u] + pre2[g][e2[u]] + base2[e2[u]];
        if (fl[u] && (p2 < CAP)) {
            const size_t o = tb + e2[u] * CAP + p2;
            dsp[o] = 1.0f;
            cmb[o] = r[u].y;
        }
    }
}

extern "C" void kernel_launch(void* const* d_in, const int* in_sizes, int n_in,
                              void* d_out, int out_size, void* d_ws, size_t ws_size,
                              hipStream_t stream)
{
    const float* x = (const float*)d_in[0];
    const float* W = (const float*)d_in[1];
    float* out = (float*)d_out;
    char* ws = (char*)d_ws;

    float4* recs  = (float4*)(ws);
    float*  dens  = (float*)(ws + 524288);

    // zero whole output (both tensors + loss slot) at the measured 134us
    // floor (includes poison-writeback absorption); stream-ordered,
    // graph-capturable.
    hipMemsetAsync(d_out, 0, (size_t)out_size, stream);

    gating_kernel<<<256, 1024, 0, stream>>>(x, W, recs, dens);
    scan_scatter_kernel<<<8, 1024, 0, stream>>>(recs, dens, out);
}